// Round 7
// baseline (280.138 us; speedup 1.0000x reference)
//
#include <hip/hip_runtime.h>

// Problem constants
#define C_DIM   256
#define K_CODES 1024
#define HW      1024
#define NPOS    32768            // B*H*W
#define ZQ_ELEMS 8388608         // B*C*H*W

typedef float  f32x4  __attribute__((ext_vector_type(4)));
typedef __bf16 bf16x8 __attribute__((ext_vector_type(8)));

struct Cand { float s0, s1; int i0, i1; };

// workspace byte offsets
#define OFF_EF    0                      // 1024 f32
#define OFF_BB    4096                   // 512 KB packed bf16 codebook image
#define OFF_IDX   (4096 + 524288)        // 32768 int
#define OFF_LIST  (OFF_IDX + 131072)     // 32768 int
#define OFF_COUNT (OFF_LIST + 131072)    // int
#define OFF_LSUM  (OFF_COUNT + 8)        // double

#define TAU 6e-4f

// ---------------------------------------------------------------------------
// k1: faithful fp32 ||e_k||^2 (numpy pairwise emulation, validated round 2)
//     + pack codebook to chunk-linear swizzled bf16 image Bb + init scalars.
// ---------------------------------------------------------------------------
__global__ __launch_bounds__(256) void k1_prep(const float* __restrict__ emb,
                                               float* __restrict__ Ef,
                                               char* __restrict__ Bb,
                                               int* __restrict__ count,
                                               double* __restrict__ lsum) {
    const int k = blockIdx.x * 256 + threadIdx.x;
    if (k == 0) { *count = 0; *lsum = 0.0; }
    const float* a = emb + (size_t)k * C_DIM;

    float blk[2];
#pragma unroll
    for (int h = 0; h < 2; ++h) {
        const float* p = a + h * 128;
        float4 v0 = *reinterpret_cast<const float4*>(p);
        float4 v1 = *reinterpret_cast<const float4*>(p + 4);
        float r[8];
        r[0] = __fmul_rn(v0.x, v0.x); r[1] = __fmul_rn(v0.y, v0.y);
        r[2] = __fmul_rn(v0.z, v0.z); r[3] = __fmul_rn(v0.w, v0.w);
        r[4] = __fmul_rn(v1.x, v1.x); r[5] = __fmul_rn(v1.y, v1.y);
        r[6] = __fmul_rn(v1.z, v1.z); r[7] = __fmul_rn(v1.w, v1.w);
        for (int i = 8; i < 128; i += 8) {
            float4 w0 = *reinterpret_cast<const float4*>(p + i);
            float4 w1 = *reinterpret_cast<const float4*>(p + i + 4);
            r[0] = __fadd_rn(r[0], __fmul_rn(w0.x, w0.x));
            r[1] = __fadd_rn(r[1], __fmul_rn(w0.y, w0.y));
            r[2] = __fadd_rn(r[2], __fmul_rn(w0.z, w0.z));
            r[3] = __fadd_rn(r[3], __fmul_rn(w0.w, w0.w));
            r[4] = __fadd_rn(r[4], __fmul_rn(w1.x, w1.x));
            r[5] = __fadd_rn(r[5], __fmul_rn(w1.y, w1.y));
            r[6] = __fadd_rn(r[6], __fmul_rn(w1.z, w1.z));
            r[7] = __fadd_rn(r[7], __fmul_rn(w1.w, w1.w));
        }
        blk[h] = __fadd_rn(__fadd_rn(__fadd_rn(r[0], r[1]), __fadd_rn(r[2], r[3])),
                           __fadd_rn(__fadd_rn(r[4], r[5]), __fadd_rn(r[6], r[7])));
    }
    Ef[k] = __fadd_rn(blk[0], blk[1]);

    const int r = k & 63, chunk = k >> 6;
    const int xr = ((r ^ (r >> 2)) & 3) << 4;
    char* base = Bb + (size_t)chunk * 32768 + r * 64;
#pragma unroll
    for (int s = 0; s < 8; ++s) {
        const float* ep = a + s * 32;
        char* sb = base + s * 4096;
#pragma unroll
        for (int g = 0; g < 4; ++g) {
            union { __bf16 h[8]; uint4 v; } pk;
#pragma unroll
            for (int j = 0; j < 8; ++j) pk.h[j] = (__bf16)ep[g * 8 + j];
            *reinterpret_cast<uint4*>(sb + ((g * 16) ^ xr)) = pk.v;
        }
    }
}

// ---------------------------------------------------------------------------
// k2: MFMA scoring GEMM (round-6 structure, unchanged this round).
// ---------------------------------------------------------------------------
__global__ __launch_bounds__(512, 2) void k2_gemm(const float* __restrict__ z,
                                                  const char* __restrict__ Bb,
                                                  const float* __restrict__ Ef,
                                                  int* __restrict__ idxf,
                                                  int* __restrict__ list,
                                                  int* __restrict__ count) {
    __shared__ char smem[131072];          // 64KB A + 2x32KB B (Cand reuses A)
    char* As = smem;
    char* Bs = smem + 65536;

    const int t    = threadIdx.x;
    const int bidx = blockIdx.x;
    const int lane = t & 63;
    const int l15  = lane & 15, kg = lane >> 4;
    const int wid  = t >> 6;
    const int wM   = wid >> 1, wN = wid & 1;

    uint4 stg[4];
#pragma unroll
    for (int i = 0; i < 4; ++i)
        stg[i] = *reinterpret_cast<const uint4*>(Bb + i * 8192 + t * 16);

    const float* zt = z + (size_t)(bidx >> 3) * (C_DIM * HW) + (bidx & 7) * 128;
#pragma unroll
    for (int p = 0; p < 8; ++p) {
        const int pi  = p * 512 + t;
        const int c2  = pi >> 5;
        const int hwg = pi & 31;
        const float* p0 = zt + (size_t)(2 * c2) * HW + hwg * 4;
        const float4 f0 = *reinterpret_cast<const float4*>(p0);
        const float4 f1 = *reinterpret_cast<const float4*>(p0 + HW);
        const float a0v[4] = {f0.x, f0.y, f0.z, f0.w};
        const float a1v[4] = {f1.x, f1.y, f1.z, f1.w};
#pragma unroll
        for (int i = 0; i < 4; ++i) {
            const int hw = hwg * 4 + i;
            const int xr = ((hw ^ (hw >> 2)) & 7) << 4;
            const int koff = (c2 * 4) ^ xr;
            union { __bf16 h[2]; unsigned int u; } ph;
            ph.h[0] = (__bf16)a0v[i];
            ph.h[1] = (__bf16)a1v[i];
            *reinterpret_cast<unsigned int*>(As + hw * 512 + koff) = ph.u;
        }
    }
#pragma unroll
    for (int i = 0; i < 4; ++i)
        *reinterpret_cast<uint4*>(Bs + i * 8192 + t * 16) = stg[i];
    __syncthreads();

    bf16x8 af[2][8];
#pragma unroll
    for (int mi = 0; mi < 2; ++mi) {
        const int row = wM * 32 + mi * 16 + l15;
        const int axr = ((row ^ (row >> 2)) & 7) << 4;
#pragma unroll
        for (int ks = 0; ks < 8; ++ks)
            af[mi][ks] = *reinterpret_cast<const bf16x8*>(
                As + row * 512 + ((ks * 64 + kg * 16) ^ axr));
    }

    int brow[2], bxr[2];
#pragma unroll
    for (int ni = 0; ni < 2; ++ni) {
        brow[ni] = wN * 32 + ni * 16 + l15;
        bxr[ni]  = ((brow[ni] ^ (brow[ni] >> 2)) & 3) << 4;
    }

    float bs0[8], bs1[8];
    int   bi0[8], bi1[8];
#pragma unroll
    for (int s = 0; s < 8; ++s) { bs0[s] = 1e30f; bs1[s] = 1e30f; bi0[s] = 1 << 29; bi1[s] = 1 << 29; }

    for (int g = 0; g < 16; ++g) {
        if (g < 15) {
#pragma unroll
            for (int i = 0; i < 4; ++i)
                stg[i] = *reinterpret_cast<const uint4*>(
                    Bb + (size_t)(g + 1) * 32768 + i * 8192 + t * 16);
        }
        const char* bbuf = Bs + (g & 1) * 32768;
        f32x4 acc[2][2];
#pragma unroll
        for (int mi = 0; mi < 2; ++mi)
#pragma unroll
        for (int ni = 0; ni < 2; ++ni) acc[mi][ni] = f32x4{0.f, 0.f, 0.f, 0.f};

#pragma unroll
        for (int ks = 0; ks < 8; ++ks) {
            bf16x8 bf[2];
#pragma unroll
            for (int ni = 0; ni < 2; ++ni)
                bf[ni] = *reinterpret_cast<const bf16x8*>(
                    bbuf + ks * 4096 + brow[ni] * 64 + ((kg * 16) ^ bxr[ni]));
#pragma unroll
            for (int mi = 0; mi < 2; ++mi)
#pragma unroll
            for (int ni = 0; ni < 2; ++ni)
                acc[mi][ni] = __builtin_amdgcn_mfma_f32_16x16x32_bf16(
                    af[mi][ks], bf[ni], acc[mi][ni], 0, 0, 0);
        }

        if (g < 15) {
            char* nbuf = Bs + ((g + 1) & 1) * 32768;
#pragma unroll
            for (int i = 0; i < 4; ++i)
                *reinterpret_cast<uint4*>(nbuf + i * 8192 + t * 16) = stg[i];
        }

#pragma unroll
        for (int ni = 0; ni < 2; ++ni) {
            const int code = g * 64 + brow[ni];
            const float ef = Ef[code];
#pragma unroll
            for (int mi = 0; mi < 2; ++mi) {
#pragma unroll
                for (int rr = 0; rr < 4; ++rr) {
                    const float s = ef - 2.0f * acc[mi][ni][rr];
                    const int slot = mi * 4 + rr;
                    if (s < bs0[slot] || (s == bs0[slot] && code < bi0[slot])) {
                        bs1[slot] = bs0[slot]; bi1[slot] = bi0[slot];
                        bs0[slot] = s; bi0[slot] = code;
                    } else if (s < bs1[slot] || (s == bs1[slot] && code < bi1[slot])) {
                        bs1[slot] = s; bi1[slot] = code;
                    }
                }
            }
        }
        __syncthreads();
    }

#pragma unroll
    for (int slot = 0; slot < 8; ++slot) {
        float s0 = bs0[slot], s1 = bs1[slot];
        int   i0 = bi0[slot], i1 = bi1[slot];
#pragma unroll
        for (int m = 1; m <= 8; m <<= 1) {
            const float os0 = __shfl_xor(s0, m), os1 = __shfl_xor(s1, m);
            const int   oi0 = __shfl_xor(i0, m), oi1 = __shfl_xor(i1, m);
            if (os0 < s0 || (os0 == s0 && oi0 < i0)) {
                s1 = s0; i1 = i0; s0 = os0; i0 = oi0;
                if (os1 < s1 || (os1 == s1 && oi1 < i1)) { s1 = os1; i1 = oi1; }
            } else if (os0 < s1 || (os0 == s1 && oi0 < i1)) { s1 = os0; i1 = oi0; }
        }
        bs0[slot] = s0; bs1[slot] = s1; bi0[slot] = i0; bi1[slot] = i1;
    }

    Cand* cl = reinterpret_cast<Cand*>(smem);
    if (l15 == 0) {
#pragma unroll
        for (int slot = 0; slot < 8; ++slot) {
            const int mi = slot >> 2, rr = slot & 3;
            const int row = wM * 32 + mi * 16 + kg * 4 + rr;
            Cand c; c.s0 = bs0[slot]; c.s1 = bs1[slot]; c.i0 = bi0[slot]; c.i1 = bi1[slot];
            cl[row * 2 + wN] = c;
        }
    }
    __syncthreads();

    if (t < 128) {
        Cand a = cl[t * 2];
        const Cand b = cl[t * 2 + 1];
        if (b.s0 < a.s0 || (b.s0 == a.s0 && b.i0 < a.i0)) {
            const float ts = a.s0; const int ti = a.i0;
            a.s0 = b.s0; a.i0 = b.i0;
            a.s1 = ts;   a.i1 = ti;
            if (b.s1 < a.s1 || (b.s1 == a.s1 && b.i1 < a.i1)) { a.s1 = b.s1; a.i1 = b.i1; }
        } else if (b.s0 < a.s1 || (b.s0 == a.s1 && b.i0 < a.i1)) { a.s1 = b.s0; a.i1 = b.i0; }
        const int n = bidx * 128 + t;
        idxf[n] = a.i0;
        if (a.s1 - a.s0 < TAU) {
            const int p = atomicAdd(count, 1);
            list[p] = n;
        }
    }
}

// ---------------------------------------------------------------------------
// k3 v3: direct-L2 faithful fp32 re-score, high TLP. 8 rows/group, 4096
// blocks (<=1 group/block even if all rows flagged). Each thread owns 4
// consecutive codes; 32 independent sequential-FMA chains over ascending c
// (validated numerics: fl(fl(zn+en) - fl(2*dot)), first-wins argmin).
// e reads go straight to L2 (64B-line-efficient); z rows broadcast from LDS.
// ---------------------------------------------------------------------------
#define RB3 8
__global__ __launch_bounds__(256, 4) void k3_refine(const float* __restrict__ z,
                                                    const float* __restrict__ emb,
                                                    const float* __restrict__ Ef,
                                                    const int* __restrict__ list,
                                                    const int* __restrict__ count,
                                                    int* __restrict__ idxf) {
    __shared__ __align__(16) float zs[C_DIM][RB3];   // 8 KB, [c][row]
    __shared__ int   rowsh[RB3];
    __shared__ float znsh[RB3];
    __shared__ float wd[4][RB3];
    __shared__ int   wi[4][RB3];

    const int t = threadIdx.x;
    const int lane = t & 63, w = t >> 6;
    const int cnt = *count;

    for (int g0 = blockIdx.x * RB3; g0 < cnt; g0 += gridDim.x * RB3) {
        const int nrows = min(RB3, cnt - g0);
        if (t < RB3) rowsh[t] = list[g0 + min(t, nrows - 1)];
        __syncthreads();

        {   // gather z rows -> zs[c][r]
            const int r = t & 7, cg = t >> 3;
            const int row = rowsh[r];
            const int b = row >> 10, hw = row & 1023;
            const float* zp = z + ((size_t)b * C_DIM + cg * 8) * HW + hw;
#pragma unroll
            for (int i = 0; i < 8; ++i)
                zs[cg * 8 + i][r] = zp[(size_t)i * HW];
        }
        __syncthreads();

        if (t < RB3) {   // numpy pairwise ||z||^2 (validated emulation)
            float blk[2];
#pragma unroll
            for (int h = 0; h < 2; ++h) {
                float rr[8];
#pragma unroll
                for (int j = 0; j < 8; ++j) {
                    const float v = zs[h * 128 + j][t];
                    rr[j] = __fmul_rn(v, v);
                }
                for (int i = 8; i < 128; i += 8) {
#pragma unroll
                    for (int j = 0; j < 8; ++j) {
                        const float v = zs[h * 128 + i + j][t];
                        rr[j] = __fadd_rn(rr[j], __fmul_rn(v, v));
                    }
                }
                blk[h] = __fadd_rn(__fadd_rn(__fadd_rn(rr[0], rr[1]), __fadd_rn(rr[2], rr[3])),
                                   __fadd_rn(__fadd_rn(rr[4], rr[5]), __fadd_rn(rr[6], rr[7])));
            }
            znsh[t] = __fadd_rn(blk[0], blk[1]);
        }
        __syncthreads();

        // 4 codes x 8 rows = 32 independent sequential chains, c ascending
        float acc[4][RB3];
#pragma unroll
        for (int q = 0; q < 4; ++q)
#pragma unroll
        for (int r = 0; r < RB3; ++r) acc[q][r] = 0.f;

        const float* e0 = emb + (size_t)(t * 4) * C_DIM;
        for (int c = 0; c < C_DIM; c += 4) {
            const float4 ev0 = *reinterpret_cast<const float4*>(e0 + c);
            const float4 ev1 = *reinterpret_cast<const float4*>(e0 + C_DIM + c);
            const float4 ev2 = *reinterpret_cast<const float4*>(e0 + 2 * C_DIM + c);
            const float4 ev3 = *reinterpret_cast<const float4*>(e0 + 3 * C_DIM + c);
            const float eq[4][4] = {{ev0.x, ev0.y, ev0.z, ev0.w},
                                    {ev1.x, ev1.y, ev1.z, ev1.w},
                                    {ev2.x, ev2.y, ev2.z, ev2.w},
                                    {ev3.x, ev3.y, ev3.z, ev3.w}};
#pragma unroll
            for (int j = 0; j < 4; ++j) {
                float zv[RB3];
                *reinterpret_cast<float4*>(&zv[0]) = *reinterpret_cast<const float4*>(&zs[c + j][0]);
                *reinterpret_cast<float4*>(&zv[4]) = *reinterpret_cast<const float4*>(&zs[c + j][4]);
#pragma unroll
                for (int q = 0; q < 4; ++q)
#pragma unroll
                for (int r = 0; r < RB3; ++r)
                    acc[q][r] = __fmaf_rn(zv[r], eq[q][j], acc[q][r]);
            }
        }

        // epilogue: d = fl(fl(zn+en) - fl(2*dot)), first-wins argmin
        float bd[RB3]; int bi[RB3];
#pragma unroll
        for (int r = 0; r < RB3; ++r) { bd[r] = 1e30f; bi[r] = 1 << 29; }
#pragma unroll
        for (int q = 0; q < 4; ++q) {
            const int code = t * 4 + q;
            const float ef = Ef[code];
#pragma unroll
            for (int r = 0; r < RB3; ++r) {
                const float dk = __fsub_rn(__fadd_rn(znsh[r], ef), __fmul_rn(2.0f, acc[q][r]));
                if (dk < bd[r]) { bd[r] = dk; bi[r] = code; }
            }
        }
#pragma unroll
        for (int m = 1; m <= 32; m <<= 1) {
#pragma unroll
            for (int r = 0; r < RB3; ++r) {
                const float od = __shfl_xor(bd[r], m);
                const int   oi = __shfl_xor(bi[r], m);
                if (od < bd[r] || (od == bd[r] && oi < bi[r])) { bd[r] = od; bi[r] = oi; }
            }
        }
        if (lane == 0) {
#pragma unroll
            for (int r = 0; r < RB3; ++r) { wd[w][r] = bd[r]; wi[w][r] = bi[r]; }
        }
        __syncthreads();
        if (t < RB3) {
            float d = wd[0][t]; int i = wi[0][t];
#pragma unroll
            for (int ww = 1; ww < 4; ++ww) {
                if (wd[ww][t] < d || (wd[ww][t] == d && wi[ww][t] < i)) { d = wd[ww][t]; i = wi[ww][t]; }
            }
            if (t < nrows) idxf[rowsh[t]] = i;
        }
        __syncthreads();
    }
}

// ---------------------------------------------------------------------------
// k4: zq straight-through + fp64 loss partial + indices-as-float
// ---------------------------------------------------------------------------
__global__ __launch_bounds__(256) void k4_out(const float* __restrict__ z,
                                              const float* __restrict__ emb,
                                              const int* __restrict__ idxf,
                                              float* __restrict__ out,
                                              double* __restrict__ lsum) {
    const int gid = blockIdx.x * 256 + threadIdx.x;
    if (gid < NPOS) out[(size_t)ZQ_ELEMS + 3 + gid] = (float)idxf[gid];

    const size_t stride = (size_t)gridDim.x * 256;
    double acc = 0.0;
    for (size_t v = (size_t)gid; v < (ZQ_ELEMS / 4); v += stride) {
        const size_t e = v * 4;
        const int hw = (int)(e & 1023);
        const int bc = (int)(e >> 10);
        const int c  = bc & 255;
        const int b  = bc >> 8;
        const int n  = b * 1024 + hw;
        const float4 zv = *reinterpret_cast<const float4*>(z + e);
        const int j0 = idxf[n], j1 = idxf[n + 1], j2 = idxf[n + 2], j3 = idxf[n + 3];
        const float e0 = emb[(size_t)j0 * C_DIM + c];
        const float e1 = emb[(size_t)j1 * C_DIM + c];
        const float e2 = emb[(size_t)j2 * C_DIM + c];
        const float e3 = emb[(size_t)j3 * C_DIM + c];
        float4 o;
        o.x = zv.x + (e0 - zv.x);
        o.y = zv.y + (e1 - zv.y);
        o.z = zv.z + (e2 - zv.z);
        o.w = zv.w + (e3 - zv.w);
        *reinterpret_cast<float4*>(out + e) = o;
        const double d0 = (double)e0 - (double)zv.x;
        const double d1 = (double)e1 - (double)zv.y;
        const double d2 = (double)e2 - (double)zv.z;
        const double d3 = (double)e3 - (double)zv.w;
        acc += d0 * d0 + d1 * d1 + d2 * d2 + d3 * d3;
    }
#pragma unroll
    for (int off = 32; off > 0; off >>= 1) acc += __shfl_down(acc, off);
    __shared__ double wsum[4];
    const int w = threadIdx.x >> 6, lanei = threadIdx.x & 63;
    if (lanei == 0) wsum[w] = acc;
    __syncthreads();
    if (threadIdx.x == 0) atomicAdd(lsum, wsum[0] + wsum[1] + wsum[2] + wsum[3]);
}

__global__ void k5_loss(const double* __restrict__ lsum, float* __restrict__ out) {
    const double m = *lsum / (double)ZQ_ELEMS;
    const float cm = (float)(0.25 * m);
    const float cb = (float)m;
    out[ZQ_ELEMS]     = cm + cb;
    out[ZQ_ELEMS + 1] = cm;
    out[ZQ_ELEMS + 2] = cb;
}

extern "C" void kernel_launch(void* const* d_in, const int* in_sizes, int n_in,
                              void* d_out, int out_size, void* d_ws, size_t ws_size,
                              hipStream_t stream) {
    const float* z   = (const float*)d_in[0];
    const float* emb = (const float*)d_in[1];
    float* out = (float*)d_out;
    char* ws = (char*)d_ws;

    float*  Ef    = (float*)(ws + OFF_EF);
    char*   Bb    = ws + OFF_BB;
    int*    idxf  = (int*)(ws + OFF_IDX);
    int*    list  = (int*)(ws + OFF_LIST);
    int*    count = (int*)(ws + OFF_COUNT);
    double* lsum  = (double*)(ws + OFF_LSUM);

    k1_prep<<<4, 256, 0, stream>>>(emb, Ef, Bb, count, lsum);
    k2_gemm<<<256, 512, 0, stream>>>(z, Bb, Ef, idxf, list, count);
    k3_refine<<<4096, 256, 0, stream>>>(z, emb, Ef, list, count, idxf);
    k4_out<<<2048, 256, 0, stream>>>(z, emb, idxf, out, lsum);
    k5_loss<<<1, 1, 0, stream>>>(lsum, out);
}

// Round 8
// 198.041 us; speedup vs baseline: 1.4145x; 1.4145x over previous
//
#include <hip/hip_runtime.h>

// Problem constants
#define C_DIM   256
#define K_CODES 1024
#define HW      1024
#define NPOS    32768            // B*H*W
#define ZQ_ELEMS 8388608         // B*C*H*W

typedef float  f32x4  __attribute__((ext_vector_type(4)));
typedef __bf16 bf16x8 __attribute__((ext_vector_type(8)));

struct Cand { float s0, s1; int i0, i1; };

// workspace byte offsets
#define OFF_EF    0                      // 1024 f32
#define OFF_BB    4096                   // 512 KB packed bf16 codebook image
#define OFF_IDX   (4096 + 524288)        // 32768 int
#define OFF_LIST  (OFF_IDX + 131072)     // 32768 int
#define OFF_COUNT (OFF_LIST + 131072)    // int
#define OFF_LSUM  (OFF_COUNT + 8)        // double
#define OFF_ET    790656                 // 1 MB f32 transposed codebook [c][k]

#define TAU 6e-4f

// ---------------------------------------------------------------------------
// k1: faithful fp32 ||e_k||^2 (numpy pairwise emulation, validated round 2)
//     + pack codebook to chunk-linear swizzled bf16 image Bb + init scalars.
// ---------------------------------------------------------------------------
__global__ __launch_bounds__(256) void k1_prep(const float* __restrict__ emb,
                                               float* __restrict__ Ef,
                                               char* __restrict__ Bb,
                                               int* __restrict__ count,
                                               double* __restrict__ lsum) {
    const int k = blockIdx.x * 256 + threadIdx.x;
    if (k == 0) { *count = 0; *lsum = 0.0; }
    const float* a = emb + (size_t)k * C_DIM;

    float blk[2];
#pragma unroll
    for (int h = 0; h < 2; ++h) {
        const float* p = a + h * 128;
        float4 v0 = *reinterpret_cast<const float4*>(p);
        float4 v1 = *reinterpret_cast<const float4*>(p + 4);
        float r[8];
        r[0] = __fmul_rn(v0.x, v0.x); r[1] = __fmul_rn(v0.y, v0.y);
        r[2] = __fmul_rn(v0.z, v0.z); r[3] = __fmul_rn(v0.w, v0.w);
        r[4] = __fmul_rn(v1.x, v1.x); r[5] = __fmul_rn(v1.y, v1.y);
        r[6] = __fmul_rn(v1.z, v1.z); r[7] = __fmul_rn(v1.w, v1.w);
        for (int i = 8; i < 128; i += 8) {
            float4 w0 = *reinterpret_cast<const float4*>(p + i);
            float4 w1 = *reinterpret_cast<const float4*>(p + i + 4);
            r[0] = __fadd_rn(r[0], __fmul_rn(w0.x, w0.x));
            r[1] = __fadd_rn(r[1], __fmul_rn(w0.y, w0.y));
            r[2] = __fadd_rn(r[2], __fmul_rn(w0.z, w0.z));
            r[3] = __fadd_rn(r[3], __fmul_rn(w0.w, w0.w));
            r[4] = __fadd_rn(r[4], __fmul_rn(w1.x, w1.x));
            r[5] = __fadd_rn(r[5], __fmul_rn(w1.y, w1.y));
            r[6] = __fadd_rn(r[6], __fmul_rn(w1.z, w1.z));
            r[7] = __fadd_rn(r[7], __fmul_rn(w1.w, w1.w));
        }
        blk[h] = __fadd_rn(__fadd_rn(__fadd_rn(r[0], r[1]), __fadd_rn(r[2], r[3])),
                           __fadd_rn(__fadd_rn(r[4], r[5]), __fadd_rn(r[6], r[7])));
    }
    Ef[k] = __fadd_rn(blk[0], blk[1]);

    const int r = k & 63, chunk = k >> 6;
    const int xr = ((r ^ (r >> 2)) & 3) << 4;
    char* base = Bb + (size_t)chunk * 32768 + r * 64;
#pragma unroll
    for (int s = 0; s < 8; ++s) {
        const float* ep = a + s * 32;
        char* sb = base + s * 4096;
#pragma unroll
        for (int g = 0; g < 4; ++g) {
            union { __bf16 h[8]; uint4 v; } pk;
#pragma unroll
            for (int j = 0; j < 8; ++j) pk.h[j] = (__bf16)ep[g * 8 + j];
            *reinterpret_cast<uint4*>(sb + ((g * 16) ^ xr)) = pk.v;
        }
    }
}

// ---------------------------------------------------------------------------
// k1t: codebook transpose emb[k][c] -> embT[c][k] via 64x64 LDS tiles.
// Both global phases coalesced; LDS padded (65) = conflict-free.
// ---------------------------------------------------------------------------
__global__ __launch_bounds__(256) void k1t(const float* __restrict__ emb,
                                           float* __restrict__ embT) {
    __shared__ float tile[64][65];
    const int l = threadIdx.x & 63, w = threadIdx.x >> 6;
    const int k0 = (blockIdx.x & 15) * 64;
    const int c0 = (blockIdx.x >> 4) * 64;
#pragma unroll
    for (int i = 0; i < 16; ++i)
        tile[l][w * 16 + i] = emb[(size_t)(k0 + w * 16 + i) * C_DIM + c0 + l];
    __syncthreads();
#pragma unroll
    for (int i = 0; i < 16; ++i)
        embT[(size_t)(c0 + w * 16 + i) * K_CODES + k0 + l] = tile[w * 16 + i][l];
}

// ---------------------------------------------------------------------------
// k2: MFMA scoring GEMM (round-6 structure, unchanged).
// ---------------------------------------------------------------------------
__global__ __launch_bounds__(512, 2) void k2_gemm(const float* __restrict__ z,
                                                  const char* __restrict__ Bb,
                                                  const float* __restrict__ Ef,
                                                  int* __restrict__ idxf,
                                                  int* __restrict__ list,
                                                  int* __restrict__ count) {
    __shared__ char smem[131072];          // 64KB A + 2x32KB B (Cand reuses A)
    char* As = smem;
    char* Bs = smem + 65536;

    const int t    = threadIdx.x;
    const int bidx = blockIdx.x;
    const int lane = t & 63;
    const int l15  = lane & 15, kg = lane >> 4;
    const int wid  = t >> 6;
    const int wM   = wid >> 1, wN = wid & 1;

    uint4 stg[4];
#pragma unroll
    for (int i = 0; i < 4; ++i)
        stg[i] = *reinterpret_cast<const uint4*>(Bb + i * 8192 + t * 16);

    const float* zt = z + (size_t)(bidx >> 3) * (C_DIM * HW) + (bidx & 7) * 128;
#pragma unroll
    for (int p = 0; p < 8; ++p) {
        const int pi  = p * 512 + t;
        const int c2  = pi >> 5;
        const int hwg = pi & 31;
        const float* p0 = zt + (size_t)(2 * c2) * HW + hwg * 4;
        const float4 f0 = *reinterpret_cast<const float4*>(p0);
        const float4 f1 = *reinterpret_cast<const float4*>(p0 + HW);
        const float a0v[4] = {f0.x, f0.y, f0.z, f0.w};
        const float a1v[4] = {f1.x, f1.y, f1.z, f1.w};
#pragma unroll
        for (int i = 0; i < 4; ++i) {
            const int hw = hwg * 4 + i;
            const int xr = ((hw ^ (hw >> 2)) & 7) << 4;
            const int koff = (c2 * 4) ^ xr;
            union { __bf16 h[2]; unsigned int u; } ph;
            ph.h[0] = (__bf16)a0v[i];
            ph.h[1] = (__bf16)a1v[i];
            *reinterpret_cast<unsigned int*>(As + hw * 512 + koff) = ph.u;
        }
    }
#pragma unroll
    for (int i = 0; i < 4; ++i)
        *reinterpret_cast<uint4*>(Bs + i * 8192 + t * 16) = stg[i];
    __syncthreads();

    bf16x8 af[2][8];
#pragma unroll
    for (int mi = 0; mi < 2; ++mi) {
        const int row = wM * 32 + mi * 16 + l15;
        const int axr = ((row ^ (row >> 2)) & 7) << 4;
#pragma unroll
        for (int ks = 0; ks < 8; ++ks)
            af[mi][ks] = *reinterpret_cast<const bf16x8*>(
                As + row * 512 + ((ks * 64 + kg * 16) ^ axr));
    }

    int brow[2], bxr[2];
#pragma unroll
    for (int ni = 0; ni < 2; ++ni) {
        brow[ni] = wN * 32 + ni * 16 + l15;
        bxr[ni]  = ((brow[ni] ^ (brow[ni] >> 2)) & 3) << 4;
    }

    float bs0[8], bs1[8];
    int   bi0[8], bi1[8];
#pragma unroll
    for (int s = 0; s < 8; ++s) { bs0[s] = 1e30f; bs1[s] = 1e30f; bi0[s] = 1 << 29; bi1[s] = 1 << 29; }

    for (int g = 0; g < 16; ++g) {
        if (g < 15) {
#pragma unroll
            for (int i = 0; i < 4; ++i)
                stg[i] = *reinterpret_cast<const uint4*>(
                    Bb + (size_t)(g + 1) * 32768 + i * 8192 + t * 16);
        }
        const char* bbuf = Bs + (g & 1) * 32768;
        f32x4 acc[2][2];
#pragma unroll
        for (int mi = 0; mi < 2; ++mi)
#pragma unroll
        for (int ni = 0; ni < 2; ++ni) acc[mi][ni] = f32x4{0.f, 0.f, 0.f, 0.f};

#pragma unroll
        for (int ks = 0; ks < 8; ++ks) {
            bf16x8 bf[2];
#pragma unroll
            for (int ni = 0; ni < 2; ++ni)
                bf[ni] = *reinterpret_cast<const bf16x8*>(
                    bbuf + ks * 4096 + brow[ni] * 64 + ((kg * 16) ^ bxr[ni]));
#pragma unroll
            for (int mi = 0; mi < 2; ++mi)
#pragma unroll
            for (int ni = 0; ni < 2; ++ni)
                acc[mi][ni] = __builtin_amdgcn_mfma_f32_16x16x32_bf16(
                    af[mi][ks], bf[ni], acc[mi][ni], 0, 0, 0);
        }

        if (g < 15) {
            char* nbuf = Bs + ((g + 1) & 1) * 32768;
#pragma unroll
            for (int i = 0; i < 4; ++i)
                *reinterpret_cast<uint4*>(nbuf + i * 8192 + t * 16) = stg[i];
        }

#pragma unroll
        for (int ni = 0; ni < 2; ++ni) {
            const int code = g * 64 + brow[ni];
            const float ef = Ef[code];
#pragma unroll
            for (int mi = 0; mi < 2; ++mi) {
#pragma unroll
                for (int rr = 0; rr < 4; ++rr) {
                    const float s = ef - 2.0f * acc[mi][ni][rr];
                    const int slot = mi * 4 + rr;
                    if (s < bs0[slot] || (s == bs0[slot] && code < bi0[slot])) {
                        bs1[slot] = bs0[slot]; bi1[slot] = bi0[slot];
                        bs0[slot] = s; bi0[slot] = code;
                    } else if (s < bs1[slot] || (s == bs1[slot] && code < bi1[slot])) {
                        bs1[slot] = s; bi1[slot] = code;
                    }
                }
            }
        }
        __syncthreads();
    }

#pragma unroll
    for (int slot = 0; slot < 8; ++slot) {
        float s0 = bs0[slot], s1 = bs1[slot];
        int   i0 = bi0[slot], i1 = bi1[slot];
#pragma unroll
        for (int m = 1; m <= 8; m <<= 1) {
            const float os0 = __shfl_xor(s0, m), os1 = __shfl_xor(s1, m);
            const int   oi0 = __shfl_xor(i0, m), oi1 = __shfl_xor(i1, m);
            if (os0 < s0 || (os0 == s0 && oi0 < i0)) {
                s1 = s0; i1 = i0; s0 = os0; i0 = oi0;
                if (os1 < s1 || (os1 == s1 && oi1 < i1)) { s1 = os1; i1 = oi1; }
            } else if (os0 < s1 || (os0 == s1 && oi0 < i1)) { s1 = os0; i1 = oi0; }
        }
        bs0[slot] = s0; bs1[slot] = s1; bi0[slot] = i0; bi1[slot] = i1;
    }

    Cand* cl = reinterpret_cast<Cand*>(smem);
    if (l15 == 0) {
#pragma unroll
        for (int slot = 0; slot < 8; ++slot) {
            const int mi = slot >> 2, rr = slot & 3;
            const int row = wM * 32 + mi * 16 + kg * 4 + rr;
            Cand c; c.s0 = bs0[slot]; c.s1 = bs1[slot]; c.i0 = bi0[slot]; c.i1 = bi1[slot];
            cl[row * 2 + wN] = c;
        }
    }
    __syncthreads();

    if (t < 128) {
        Cand a = cl[t * 2];
        const Cand b = cl[t * 2 + 1];
        if (b.s0 < a.s0 || (b.s0 == a.s0 && b.i0 < a.i0)) {
            const float ts = a.s0; const int ti = a.i0;
            a.s0 = b.s0; a.i0 = b.i0;
            a.s1 = ts;   a.i1 = ti;
            if (b.s1 < a.s1 || (b.s1 == a.s1 && b.i1 < a.i1)) { a.s1 = b.s1; a.i1 = b.i1; }
        } else if (b.s0 < a.s1 || (b.s0 == a.s1 && b.i0 < a.i1)) { a.s1 = b.s0; a.i1 = b.i0; }
        const int n = bidx * 128 + t;
        idxf[n] = a.i0;
        if (a.s1 - a.s0 < TAU) {
            const int p = atomicAdd(count, 1);
            list[p] = n;
        }
    }
}

// ---------------------------------------------------------------------------
// k3 v4: coalesced faithful fp32 re-score via transposed codebook.
// Per c: ONE wave-coalesced float4 load (embT[c][lane*4] -> this thread's 4
// consecutive codes) + 32 FMA into 4x8 chains. Numerics identical to the
// validated recipe (ascending-c sequential __fmaf_rn chains, first-wins).
// ---------------------------------------------------------------------------
#define RB3 8
__global__ __launch_bounds__(256, 4) void k3_refine(const float* __restrict__ z,
                                                    const float* __restrict__ embT,
                                                    const float* __restrict__ Ef,
                                                    const int* __restrict__ list,
                                                    const int* __restrict__ count,
                                                    int* __restrict__ idxf) {
    __shared__ __align__(16) float zs[C_DIM][RB3];   // 8 KB, [c][row]
    __shared__ int   rowsh[RB3];
    __shared__ float znsh[RB3];
    __shared__ float wd[4][RB3];
    __shared__ int   wi[4][RB3];

    const int t = threadIdx.x;
    const int lane = t & 63, w = t >> 6;
    const int cnt = *count;

    for (int g0 = blockIdx.x * RB3; g0 < cnt; g0 += gridDim.x * RB3) {
        const int nrows = min(RB3, cnt - g0);
        if (t < RB3) rowsh[t] = list[g0 + min(t, nrows - 1)];
        __syncthreads();

        {   // gather z rows -> zs[c][r]
            const int r = t & 7, cg = t >> 3;
            const int row = rowsh[r];
            const int b = row >> 10, hw = row & 1023;
            const float* zp = z + ((size_t)b * C_DIM + cg * 8) * HW + hw;
#pragma unroll
            for (int i = 0; i < 8; ++i)
                zs[cg * 8 + i][r] = zp[(size_t)i * HW];
        }
        __syncthreads();

        if (t < RB3) {   // numpy pairwise ||z||^2 (validated emulation)
            float blk[2];
#pragma unroll
            for (int h = 0; h < 2; ++h) {
                float rr[8];
#pragma unroll
                for (int j = 0; j < 8; ++j) {
                    const float v = zs[h * 128 + j][t];
                    rr[j] = __fmul_rn(v, v);
                }
                for (int i = 8; i < 128; i += 8) {
#pragma unroll
                    for (int j = 0; j < 8; ++j) {
                        const float v = zs[h * 128 + i + j][t];
                        rr[j] = __fadd_rn(rr[j], __fmul_rn(v, v));
                    }
                }
                blk[h] = __fadd_rn(__fadd_rn(__fadd_rn(rr[0], rr[1]), __fadd_rn(rr[2], rr[3])),
                                   __fadd_rn(__fadd_rn(rr[4], rr[5]), __fadd_rn(rr[6], rr[7])));
            }
            znsh[t] = __fadd_rn(blk[0], blk[1]);
        }
        __syncthreads();

        float acc[4][RB3];
#pragma unroll
        for (int q = 0; q < 4; ++q)
#pragma unroll
        for (int r = 0; r < RB3; ++r) acc[q][r] = 0.f;

        const float* ebase = embT + t * 4;
#pragma unroll 4
        for (int c = 0; c < C_DIM; ++c) {
            const float4 ev = *reinterpret_cast<const float4*>(ebase + (size_t)c * K_CODES);
            float zv[RB3];
            *reinterpret_cast<float4*>(&zv[0]) = *reinterpret_cast<const float4*>(&zs[c][0]);
            *reinterpret_cast<float4*>(&zv[4]) = *reinterpret_cast<const float4*>(&zs[c][4]);
            const float eq[4] = {ev.x, ev.y, ev.z, ev.w};
#pragma unroll
            for (int q = 0; q < 4; ++q)
#pragma unroll
            for (int r = 0; r < RB3; ++r)
                acc[q][r] = __fmaf_rn(zv[r], eq[q], acc[q][r]);
        }

        // epilogue: d = fl(fl(zn+en) - fl(2*dot)), first-wins argmin
        float bd[RB3]; int bi[RB3];
#pragma unroll
        for (int r = 0; r < RB3; ++r) { bd[r] = 1e30f; bi[r] = 1 << 29; }
#pragma unroll
        for (int q = 0; q < 4; ++q) {
            const int code = t * 4 + q;
            const float ef = Ef[code];
#pragma unroll
            for (int r = 0; r < RB3; ++r) {
                const float dk = __fsub_rn(__fadd_rn(znsh[r], ef), __fmul_rn(2.0f, acc[q][r]));
                if (dk < bd[r]) { bd[r] = dk; bi[r] = code; }
            }
        }
#pragma unroll
        for (int m = 1; m <= 32; m <<= 1) {
#pragma unroll
            for (int r = 0; r < RB3; ++r) {
                const float od = __shfl_xor(bd[r], m);
                const int   oi = __shfl_xor(bi[r], m);
                if (od < bd[r] || (od == bd[r] && oi < bi[r])) { bd[r] = od; bi[r] = oi; }
            }
        }
        if (lane == 0) {
#pragma unroll
            for (int r = 0; r < RB3; ++r) { wd[w][r] = bd[r]; wi[w][r] = bi[r]; }
        }
        __syncthreads();
        if (t < RB3) {
            float d = wd[0][t]; int i = wi[0][t];
#pragma unroll
            for (int ww = 1; ww < 4; ++ww) {
                if (wd[ww][t] < d || (wd[ww][t] == d && wi[ww][t] < i)) { d = wd[ww][t]; i = wi[ww][t]; }
            }
            if (t < nrows) idxf[rowsh[t]] = i;
        }
        __syncthreads();
    }
}

// ---------------------------------------------------------------------------
// k4: zq straight-through + fp64 loss partial + indices-as-float
// ---------------------------------------------------------------------------
__global__ __launch_bounds__(256) void k4_out(const float* __restrict__ z,
                                              const float* __restrict__ emb,
                                              const int* __restrict__ idxf,
                                              float* __restrict__ out,
                                              double* __restrict__ lsum) {
    const int gid = blockIdx.x * 256 + threadIdx.x;
    if (gid < NPOS) out[(size_t)ZQ_ELEMS + 3 + gid] = (float)idxf[gid];

    const size_t stride = (size_t)gridDim.x * 256;
    double acc = 0.0;
    for (size_t v = (size_t)gid; v < (ZQ_ELEMS / 4); v += stride) {
        const size_t e = v * 4;
        const int hw = (int)(e & 1023);
        const int bc = (int)(e >> 10);
        const int c  = bc & 255;
        const int b  = bc >> 8;
        const int n  = b * 1024 + hw;
        const float4 zv = *reinterpret_cast<const float4*>(z + e);
        const int j0 = idxf[n], j1 = idxf[n + 1], j2 = idxf[n + 2], j3 = idxf[n + 3];
        const float e0 = emb[(size_t)j0 * C_DIM + c];
        const float e1 = emb[(size_t)j1 * C_DIM + c];
        const float e2 = emb[(size_t)j2 * C_DIM + c];
        const float e3 = emb[(size_t)j3 * C_DIM + c];
        float4 o;
        o.x = zv.x + (e0 - zv.x);
        o.y = zv.y + (e1 - zv.y);
        o.z = zv.z + (e2 - zv.z);
        o.w = zv.w + (e3 - zv.w);
        *reinterpret_cast<float4*>(out + e) = o;
        const double d0 = (double)e0 - (double)zv.x;
        const double d1 = (double)e1 - (double)zv.y;
        const double d2 = (double)e2 - (double)zv.z;
        const double d3 = (double)e3 - (double)zv.w;
        acc += d0 * d0 + d1 * d1 + d2 * d2 + d3 * d3;
    }
#pragma unroll
    for (int off = 32; off > 0; off >>= 1) acc += __shfl_down(acc, off);
    __shared__ double wsum[4];
    const int w = threadIdx.x >> 6, lanei = threadIdx.x & 63;
    if (lanei == 0) wsum[w] = acc;
    __syncthreads();
    if (threadIdx.x == 0) atomicAdd(lsum, wsum[0] + wsum[1] + wsum[2] + wsum[3]);
}

__global__ void k5_loss(const double* __restrict__ lsum, float* __restrict__ out) {
    const double m = *lsum / (double)ZQ_ELEMS;
    const float cm = (float)(0.25 * m);
    const float cb = (float)m;
    out[ZQ_ELEMS]     = cm + cb;
    out[ZQ_ELEMS + 1] = cm;
    out[ZQ_ELEMS + 2] = cb;
}

extern "C" void kernel_launch(void* const* d_in, const int* in_sizes, int n_in,
                              void* d_out, int out_size, void* d_ws, size_t ws_size,
                              hipStream_t stream) {
    const float* z   = (const float*)d_in[0];
    const float* emb = (const float*)d_in[1];
    float* out = (float*)d_out;
    char* ws = (char*)d_ws;

    float*  Ef    = (float*)(ws + OFF_EF);
    char*   Bb    = ws + OFF_BB;
    int*    idxf  = (int*)(ws + OFF_IDX);
    int*    list  = (int*)(ws + OFF_LIST);
    int*    count = (int*)(ws + OFF_COUNT);
    double* lsum  = (double*)(ws + OFF_LSUM);
    float*  embT  = (float*)(ws + OFF_ET);

    k1_prep<<<4, 256, 0, stream>>>(emb, Ef, Bb, count, lsum);
    k1t<<<64, 256, 0, stream>>>(emb, embT);
    k2_gemm<<<256, 512, 0, stream>>>(z, Bb, Ef, idxf, list, count);
    k3_refine<<<4096, 256, 0, stream>>>(z, embT, Ef, list, count, idxf);
    k4_out<<<2048, 256, 0, stream>>>(z, emb, idxf, out, lsum);
    k5_loss<<<1, 1, 0, stream>>>(lsum, out);
}

// Round 9
// 161.583 us; speedup vs baseline: 1.7337x; 1.2256x over previous
//
#include <hip/hip_runtime.h>

// Problem constants
#define C_DIM   256
#define K_CODES 1024
#define HW      1024
#define NPOS    32768            // B*H*W
#define ZQ_ELEMS 8388608         // B*C*H*W

typedef float  f32x4  __attribute__((ext_vector_type(4)));
typedef __bf16 bf16x8 __attribute__((ext_vector_type(8)));

// workspace byte offsets
#define OFF_EF    0                      // 1024 f32
#define OFF_BB    4096                   // 512 KB packed bf16 codebook image
#define OFF_IDX   (4096 + 524288)        // 32768 int
#define OFF_LIST  (OFF_IDX + 131072)     // 32768 int
#define OFF_COUNT (OFF_LIST + 131072)    // int
#define OFF_LSUM  (OFF_COUNT + 8)        // double
#define OFF_ET    790656                 // 1 MB f32 transposed codebook [c][k]

#define TAU2 8e-4f   // flag margin: validated 6e-4 bf16 coverage + 1.2e-4 key-quantization + slack

static __device__ __forceinline__ uint32_t umin32(uint32_t a, uint32_t b) { return a < b ? a : b; }
static __device__ __forceinline__ uint32_t umax32(uint32_t a, uint32_t b) { return a > b ? a : b; }

// ---------------------------------------------------------------------------
// k1: faithful fp32 ||e_k||^2 (numpy pairwise emulation, validated round 2)
//     + pack codebook to chunk-linear swizzled bf16 image Bb + init scalars.
// ---------------------------------------------------------------------------
__global__ __launch_bounds__(256) void k1_prep(const float* __restrict__ emb,
                                               float* __restrict__ Ef,
                                               char* __restrict__ Bb,
                                               int* __restrict__ count,
                                               double* __restrict__ lsum) {
    const int k = blockIdx.x * 256 + threadIdx.x;
    if (k == 0) { *count = 0; *lsum = 0.0; }
    const float* a = emb + (size_t)k * C_DIM;

    float blk[2];
#pragma unroll
    for (int h = 0; h < 2; ++h) {
        const float* p = a + h * 128;
        float4 v0 = *reinterpret_cast<const float4*>(p);
        float4 v1 = *reinterpret_cast<const float4*>(p + 4);
        float r[8];
        r[0] = __fmul_rn(v0.x, v0.x); r[1] = __fmul_rn(v0.y, v0.y);
        r[2] = __fmul_rn(v0.z, v0.z); r[3] = __fmul_rn(v0.w, v0.w);
        r[4] = __fmul_rn(v1.x, v1.x); r[5] = __fmul_rn(v1.y, v1.y);
        r[6] = __fmul_rn(v1.z, v1.z); r[7] = __fmul_rn(v1.w, v1.w);
        for (int i = 8; i < 128; i += 8) {
            float4 w0 = *reinterpret_cast<const float4*>(p + i);
            float4 w1 = *reinterpret_cast<const float4*>(p + i + 4);
            r[0] = __fadd_rn(r[0], __fmul_rn(w0.x, w0.x));
            r[1] = __fadd_rn(r[1], __fmul_rn(w0.y, w0.y));
            r[2] = __fadd_rn(r[2], __fmul_rn(w0.z, w0.z));
            r[3] = __fadd_rn(r[3], __fmul_rn(w0.w, w0.w));
            r[4] = __fadd_rn(r[4], __fmul_rn(w1.x, w1.x));
            r[5] = __fadd_rn(r[5], __fmul_rn(w1.y, w1.y));
            r[6] = __fadd_rn(r[6], __fmul_rn(w1.z, w1.z));
            r[7] = __fadd_rn(r[7], __fmul_rn(w1.w, w1.w));
        }
        blk[h] = __fadd_rn(__fadd_rn(__fadd_rn(r[0], r[1]), __fadd_rn(r[2], r[3])),
                           __fadd_rn(__fadd_rn(r[4], r[5]), __fadd_rn(r[6], r[7])));
    }
    Ef[k] = __fadd_rn(blk[0], blk[1]);

    const int r = k & 63, chunk = k >> 6;
    const int xr = ((r ^ (r >> 2)) & 3) << 4;
    char* base = Bb + (size_t)chunk * 32768 + r * 64;
#pragma unroll
    for (int s = 0; s < 8; ++s) {
        const float* ep = a + s * 32;
        char* sb = base + s * 4096;
#pragma unroll
        for (int g = 0; g < 4; ++g) {
            union { __bf16 h[8]; uint4 v; } pk;
#pragma unroll
            for (int j = 0; j < 8; ++j) pk.h[j] = (__bf16)ep[g * 8 + j];
            *reinterpret_cast<uint4*>(sb + ((g * 16) ^ xr)) = pk.v;
        }
    }
}

// ---------------------------------------------------------------------------
// k1t: codebook transpose emb[k][c] -> embT[c][k] (validated round 8).
// ---------------------------------------------------------------------------
__global__ __launch_bounds__(256) void k1t(const float* __restrict__ emb,
                                           float* __restrict__ embT) {
    __shared__ float tile[64][65];
    const int l = threadIdx.x & 63, w = threadIdx.x >> 6;
    const int k0 = (blockIdx.x & 15) * 64;
    const int c0 = (blockIdx.x >> 4) * 64;
#pragma unroll
    for (int i = 0; i < 16; ++i)
        tile[l][w * 16 + i] = emb[(size_t)(k0 + w * 16 + i) * C_DIM + c0 + l];
    __syncthreads();
#pragma unroll
    for (int i = 0; i < 16; ++i)
        embT[(size_t)(c0 + w * 16 + i) * K_CODES + k0 + l] = tile[w * 16 + i][l];
}

// ---------------------------------------------------------------------------
// k2 v3: barrier-free MFMA scoring GEMM.
//  - A (z tile, 128 pos x 256 c bf16) transposed into LDS once (validated
//    path), fragments hoisted to 128 VGPRs; LDS reused for final merge.
//  - B fragments streamed DIRECTLY from global Bb (L2/L3-resident); each
//    wave-read is a contiguous 1KB block -> perfectly coalesced. No LDS
//    staging, no barriers, no bank conflicts in the main loop.
//  - Wave grid 2M x 4N: wave tile 64 rows x 16 codes/chunk; mi=4, ni=1.
//  - Branchless top-2 via order-preserving packed keys:
//    key = (bits(score+0.5) & 0xFFFFFC00) | code  (quantization 6.1e-5,
//    min-code tiebreak == first-wins; covered by TAU2 flag + exact refine).
// ---------------------------------------------------------------------------
__global__ __launch_bounds__(512, 2) void k2_gemm(const float* __restrict__ z,
                                                  const char* __restrict__ Bb,
                                                  const float* __restrict__ Ef,
                                                  int* __restrict__ idxf,
                                                  int* __restrict__ list,
                                                  int* __restrict__ count) {
    __shared__ char As[65536];             // A image; reused for final merge

    const int t    = threadIdx.x;
    const int bidx = blockIdx.x;
    const int lane = t & 63;
    const int l15  = lane & 15, kg = lane >> 4;
    const int wid  = t >> 6;
    const int wM   = wid >> 2, wN = wid & 3;   // 2M x 4N waves

    // ---- A fill: transpose z tile -> As[hw][c] bf16, row 512B, swizzled ----
    const float* zt = z + (size_t)(bidx >> 3) * (C_DIM * HW) + (bidx & 7) * 128;
#pragma unroll
    for (int p = 0; p < 8; ++p) {
        const int pi  = p * 512 + t;
        const int c2  = pi >> 5;
        const int hwg = pi & 31;
        const float* p0 = zt + (size_t)(2 * c2) * HW + hwg * 4;
        const float4 f0 = *reinterpret_cast<const float4*>(p0);
        const float4 f1 = *reinterpret_cast<const float4*>(p0 + HW);
        const float a0v[4] = {f0.x, f0.y, f0.z, f0.w};
        const float a1v[4] = {f1.x, f1.y, f1.z, f1.w};
#pragma unroll
        for (int i = 0; i < 4; ++i) {
            const int hw = hwg * 4 + i;
            const int xr = ((hw ^ (hw >> 2)) & 7) << 4;
            const int koff = (c2 * 4) ^ xr;
            union { __bf16 h[2]; unsigned int u; } ph;
            ph.h[0] = (__bf16)a0v[i];
            ph.h[1] = (__bf16)a1v[i];
            *reinterpret_cast<unsigned int*>(As + hw * 512 + koff) = ph.u;
        }
    }
    __syncthreads();

    // ---- hoist A fragments (validated layout), mi = 0..3 ----
    bf16x8 af[4][8];
#pragma unroll
    for (int mi = 0; mi < 4; ++mi) {
        const int row = wM * 64 + mi * 16 + l15;
        const int axr = ((row ^ (row >> 2)) & 7) << 4;
#pragma unroll
        for (int ks = 0; ks < 8; ++ks)
            af[mi][ks] = *reinterpret_cast<const bf16x8*>(
                As + row * 512 + ((ks * 64 + kg * 16) ^ axr));
    }

    // ---- B per-lane offset within a chunk (same mapping k1 packed) ----
    const int rB  = wN * 16 + l15;               // code within chunk
    const int swz = ((rB ^ (rB >> 2)) & 3) << 4;
    const size_t voff = (size_t)rB * 64 + ((kg * 16) ^ swz);

    uint32_t b0[16], b1[16];
#pragma unroll
    for (int s = 0; s < 16; ++s) { b0[s] = 0xFFFFFFFFu; b1[s] = 0xFFFFFFFFu; }

    for (int g = 0; g < 16; ++g) {
        const char* bgp = Bb + (size_t)g * 32768 + voff;
        union { uint4 u; bf16x8 b; } ld[8];
#pragma unroll
        for (int ks = 0; ks < 8; ++ks)
            ld[ks].u = *reinterpret_cast<const uint4*>(bgp + ks * 4096);

        const float efb = Ef[g * 64 + rB] + 0.5f;

        f32x4 acc[4];
#pragma unroll
        for (int mi = 0; mi < 4; ++mi) acc[mi] = f32x4{0.f, 0.f, 0.f, 0.f};
#pragma unroll
        for (int ks = 0; ks < 8; ++ks)
#pragma unroll
            for (int mi = 0; mi < 4; ++mi)
                acc[mi] = __builtin_amdgcn_mfma_f32_16x16x32_bf16(
                    af[mi][ks], ld[ks].b, acc[mi], 0, 0, 0);

        const uint32_t code = (uint32_t)(g * 64 + rB);
#pragma unroll
        for (int mi = 0; mi < 4; ++mi)
#pragma unroll
            for (int rr = 0; rr < 4; ++rr) {
                const float sp = __fmaf_rn(acc[mi][rr], -2.0f, efb);
                const uint32_t key = (__float_as_uint(sp) & 0xFFFFFC00u) | code;
                const int slot = mi * 4 + rr;
                const uint32_t lo = umin32(b0[slot], key);
                const uint32_t hi = umax32(b0[slot], key);
                b0[slot] = lo;
                b1[slot] = umin32(b1[slot], hi);
            }
    }

    // ---- top-2 merge across the 16 column-lanes (same kg group) ----
#pragma unroll
    for (int m = 1; m <= 8; m <<= 1) {
#pragma unroll
        for (int s = 0; s < 16; ++s) {
            const uint32_t o0 = (uint32_t)__shfl_xor((int)b0[s], m);
            const uint32_t o1 = (uint32_t)__shfl_xor((int)b1[s], m);
            const uint32_t lo = umin32(b0[s], o0);
            const uint32_t hi = umax32(b0[s], o0);
            b0[s] = lo;
            b1[s] = umin32(umin32(b1[s], o1), hi);
        }
    }

    // ---- cross-wN merge via LDS (As is dead) ----
    __syncthreads();
    uint32_t* ml = reinterpret_cast<uint32_t*>(As);   // [128 rows][4 wN][2]
    if (l15 == 0) {
#pragma unroll
        for (int s = 0; s < 16; ++s) {
            const int row = wM * 64 + (s >> 2) * 16 + kg * 4 + (s & 3);
            ml[(row * 4 + wN) * 2]     = b0[s];
            ml[(row * 4 + wN) * 2 + 1] = b1[s];
        }
    }
    __syncthreads();

    if (t < 128) {
        uint32_t k0 = 0xFFFFFFFFu, k1 = 0xFFFFFFFFu;
#pragma unroll
        for (int w = 0; w < 4; ++w) {
            const uint32_t a0 = ml[(t * 4 + w) * 2];
            const uint32_t a1 = ml[(t * 4 + w) * 2 + 1];
            const uint32_t lo = umin32(k0, a0);
            const uint32_t hi = umax32(k0, a0);
            k0 = lo;
            k1 = umin32(umin32(k1, a1), hi);
        }
        const int n = bidx * 128 + t;
        idxf[n] = (int)(k0 & 1023u);
        const float s0f = __uint_as_float(k0 & 0xFFFFFC00u);
        const float s1f = __uint_as_float(k1 & 0xFFFFFC00u);
        if (s1f - s0f < TAU2) {
            const int p = atomicAdd(count, 1);
            list[p] = n;
        }
    }
}

// ---------------------------------------------------------------------------
// k3 v4: coalesced faithful fp32 re-score via transposed codebook
// (validated round 8, unchanged).
// ---------------------------------------------------------------------------
#define RB3 8
__global__ __launch_bounds__(256, 4) void k3_refine(const float* __restrict__ z,
                                                    const float* __restrict__ embT,
                                                    const float* __restrict__ Ef,
                                                    const int* __restrict__ list,
                                                    const int* __restrict__ count,
                                                    int* __restrict__ idxf) {
    __shared__ __align__(16) float zs[C_DIM][RB3];   // 8 KB, [c][row]
    __shared__ int   rowsh[RB3];
    __shared__ float znsh[RB3];
    __shared__ float wd[4][RB3];
    __shared__ int   wi[4][RB3];

    const int t = threadIdx.x;
    const int lane = t & 63, w = t >> 6;
    const int cnt = *count;

    for (int g0 = blockIdx.x * RB3; g0 < cnt; g0 += gridDim.x * RB3) {
        const int nrows = min(RB3, cnt - g0);
        if (t < RB3) rowsh[t] = list[g0 + min(t, nrows - 1)];
        __syncthreads();

        {   // gather z rows -> zs[c][r]
            const int r = t & 7, cg = t >> 3;
            const int row = rowsh[r];
            const int b = row >> 10, hw = row & 1023;
            const float* zp = z + ((size_t)b * C_DIM + cg * 8) * HW + hw;
#pragma unroll
            for (int i = 0; i < 8; ++i)
                zs[cg * 8 + i][r] = zp[(size_t)i * HW];
        }
        __syncthreads();

        if (t < RB3) {   // numpy pairwise ||z||^2 (validated emulation)
            float blk[2];
#pragma unroll
            for (int h = 0; h < 2; ++h) {
                float rr[8];
#pragma unroll
                for (int j = 0; j < 8; ++j) {
                    const float v = zs[h * 128 + j][t];
                    rr[j] = __fmul_rn(v, v);
                }
                for (int i = 8; i < 128; i += 8) {
#pragma unroll
                    for (int j = 0; j < 8; ++j) {
                        const float v = zs[h * 128 + i + j][t];
                        rr[j] = __fadd_rn(rr[j], __fmul_rn(v, v));
                    }
                }
                blk[h] = __fadd_rn(__fadd_rn(__fadd_rn(rr[0], rr[1]), __fadd_rn(rr[2], rr[3])),
                                   __fadd_rn(__fadd_rn(rr[4], rr[5]), __fadd_rn(rr[6], rr[7])));
            }
            znsh[t] = __fadd_rn(blk[0], blk[1]);
        }
        __syncthreads();

        float acc[4][RB3];
#pragma unroll
        for (int q = 0; q < 4; ++q)
#pragma unroll
        for (int r = 0; r < RB3; ++r) acc[q][r] = 0.f;

        const float* ebase = embT + t * 4;
#pragma unroll 4
        for (int c = 0; c < C_DIM; ++c) {
            const float4 ev = *reinterpret_cast<const float4*>(ebase + (size_t)c * K_CODES);
            float zv[RB3];
            *reinterpret_cast<float4*>(&zv[0]) = *reinterpret_cast<const float4*>(&zs[c][0]);
            *reinterpret_cast<float4*>(&zv[4]) = *reinterpret_cast<const float4*>(&zs[c][4]);
            const float eq[4] = {ev.x, ev.y, ev.z, ev.w};
#pragma unroll
            for (int q = 0; q < 4; ++q)
#pragma unroll
            for (int r = 0; r < RB3; ++r)
                acc[q][r] = __fmaf_rn(zv[r], eq[q], acc[q][r]);
        }

        float bd[RB3]; int bi[RB3];
#pragma unroll
        for (int r = 0; r < RB3; ++r) { bd[r] = 1e30f; bi[r] = 1 << 29; }
#pragma unroll
        for (int q = 0; q < 4; ++q) {
            const int code = t * 4 + q;
            const float ef = Ef[code];
#pragma unroll
            for (int r = 0; r < RB3; ++r) {
                const float dk = __fsub_rn(__fadd_rn(znsh[r], ef), __fmul_rn(2.0f, acc[q][r]));
                if (dk < bd[r]) { bd[r] = dk; bi[r] = code; }
            }
        }
#pragma unroll
        for (int m = 1; m <= 32; m <<= 1) {
#pragma unroll
            for (int r = 0; r < RB3; ++r) {
                const float od = __shfl_xor(bd[r], m);
                const int   oi = __shfl_xor(bi[r], m);
                if (od < bd[r] || (od == bd[r] && oi < bi[r])) { bd[r] = od; bi[r] = oi; }
            }
        }
        if (lane == 0) {
#pragma unroll
            for (int r = 0; r < RB3; ++r) { wd[w][r] = bd[r]; wi[w][r] = bi[r]; }
        }
        __syncthreads();
        if (t < RB3) {
            float d = wd[0][t]; int i = wi[0][t];
#pragma unroll
            for (int ww = 1; ww < 4; ++ww) {
                if (wd[ww][t] < d || (wd[ww][t] == d && wi[ww][t] < i)) { d = wd[ww][t]; i = wi[ww][t]; }
            }
            if (t < nrows) idxf[rowsh[t]] = i;
        }
        __syncthreads();
    }
}

// ---------------------------------------------------------------------------
// k4: zq straight-through + fp64 loss partial + indices-as-float
// ---------------------------------------------------------------------------
__global__ __launch_bounds__(256) void k4_out(const float* __restrict__ z,
                                              const float* __restrict__ emb,
                                              const int* __restrict__ idxf,
                                              float* __restrict__ out,
                                              double* __restrict__ lsum) {
    const int gid = blockIdx.x * 256 + threadIdx.x;
    if (gid < NPOS) out[(size_t)ZQ_ELEMS + 3 + gid] = (float)idxf[gid];

    const size_t stride = (size_t)gridDim.x * 256;
    double acc = 0.0;
    for (size_t v = (size_t)gid; v < (ZQ_ELEMS / 4); v += stride) {
        const size_t e = v * 4;
        const int hw = (int)(e & 1023);
        const int bc = (int)(e >> 10);
        const int c  = bc & 255;
        const int b  = bc >> 8;
        const int n  = b * 1024 + hw;
        const float4 zv = *reinterpret_cast<const float4*>(z + e);
        const int j0 = idxf[n], j1 = idxf[n + 1], j2 = idxf[n + 2], j3 = idxf[n + 3];
        const float e0 = emb[(size_t)j0 * C_DIM + c];
        const float e1 = emb[(size_t)j1 * C_DIM + c];
        const float e2 = emb[(size_t)j2 * C_DIM + c];
        const float e3 = emb[(size_t)j3 * C_DIM + c];
        float4 o;
        o.x = zv.x + (e0 - zv.x);
        o.y = zv.y + (e1 - zv.y);
        o.z = zv.z + (e2 - zv.z);
        o.w = zv.w + (e3 - zv.w);
        *reinterpret_cast<float4*>(out + e) = o;
        const double d0 = (double)e0 - (double)zv.x;
        const double d1 = (double)e1 - (double)zv.y;
        const double d2 = (double)e2 - (double)zv.z;
        const double d3 = (double)e3 - (double)zv.w;
        acc += d0 * d0 + d1 * d1 + d2 * d2 + d3 * d3;
    }
#pragma unroll
    for (int off = 32; off > 0; off >>= 1) acc += __shfl_down(acc, off);
    __shared__ double wsum[4];
    const int w = threadIdx.x >> 6, lanei = threadIdx.x & 63;
    if (lanei == 0) wsum[w] = acc;
    __syncthreads();
    if (threadIdx.x == 0) atomicAdd(lsum, wsum[0] + wsum[1] + wsum[2] + wsum[3]);
}

__global__ void k5_loss(const double* __restrict__ lsum, float* __restrict__ out) {
    const double m = *lsum / (double)ZQ_ELEMS;
    const float cm = (float)(0.25 * m);
    const float cb = (float)m;
    out[ZQ_ELEMS]     = cm + cb;
    out[ZQ_ELEMS + 1] = cm;
    out[ZQ_ELEMS + 2] = cb;
}

extern "C" void kernel_launch(void* const* d_in, const int* in_sizes, int n_in,
                              void* d_out, int out_size, void* d_ws, size_t ws_size,
                              hipStream_t stream) {
    const float* z   = (const float*)d_in[0];
    const float* emb = (const float*)d_in[1];
    float* out = (float*)d_out;
    char* ws = (char*)d_ws;

    float*  Ef    = (float*)(ws + OFF_EF);
    char*   Bb    = ws + OFF_BB;
    int*    idxf  = (int*)(ws + OFF_IDX);
    int*    list  = (int*)(ws + OFF_LIST);
    int*    count = (int*)(ws + OFF_COUNT);
    double* lsum  = (double*)(ws + OFF_LSUM);
    float*  embT  = (float*)(ws + OFF_ET);

    k1_prep<<<4, 256, 0, stream>>>(emb, Ef, Bb, count, lsum);
    k1t<<<64, 256, 0, stream>>>(emb, embT);
    k2_gemm<<<256, 512, 0, stream>>>(z, Bb, Ef, idxf, list, count);
    k3_refine<<<4096, 256, 0, stream>>>(z, embT, Ef, list, count, idxf);
    k4_out<<<2048, 256, 0, stream>>>(z, emb, idxf, out, lsum);
    k5_loss<<<1, 1, 0, stream>>>(lsum, out);
}